// Round 1
// baseline (2507.121 us; speedup 1.0000x reference)
//
#include <hip/hip_runtime.h>
#include <float.h>
#include <math.h>

// Problem constants (fixed by setup_inputs)
constexpr int Bn = 131072;  // points
constexpr int Dn = 256;     // feature dim
constexpr int Kn = 1024;    // clusters
constexpr int Ln = 526;     // label dim
constexpr float EPSF = 1e-8f;

// GEMM tiling for the assignment kernel
constexpr int BM = 128;     // points per block
constexpr int BN = 128;     // centroids per n-tile
constexpr int BK = 16;      // d-chunk
constexpr int LDT = 132;    // padded LDS row stride (floats) -> 2-way conflicts max
constexpr int NT = Kn / BN; // 8 n-tiles
constexpr int DC = Dn / BK; // 16 d-chunks
constexpr int NTILES = NT * DC; // 128

union SMemU {
    float tiles[2][2][BK][LDT];                 // [buf][A/B][d][m], 33792 B
    struct { float t[BM][16]; int k[BM][16]; } red;
};

// ---------------- prep: c2[k] = sum(centroids[k]^2), rln[k] = sqrt(sum(rl[k]^2))
__global__ __launch_bounds__(256) void prep_kernel(
    const float* __restrict__ centroids, const float* __restrict__ rlabels,
    float* __restrict__ c2, float* __restrict__ rln)
{
    const int k = blockIdx.x;
    const int t = threadIdx.x;
    float v = centroids[k * Dn + t];            // Dn == blockDim
    float s1 = v * v;
    float s2 = 0.f;
    for (int i = t; i < Ln; i += 256) {
        float u = rlabels[(size_t)k * Ln + i];
        s2 += u * u;
    }
    for (int off = 32; off > 0; off >>= 1) {
        s1 += __shfl_down(s1, off, 64);
        s2 += __shfl_down(s2, off, 64);
    }
    __shared__ float red[8];
    const int wv = t >> 6;
    if ((t & 63) == 0) { red[wv * 2] = s1; red[wv * 2 + 1] = s2; }
    __syncthreads();
    if (t == 0) {
        c2[k]  = red[0] + red[2] + red[4] + red[6];
        rln[k] = sqrtf(red[1] + red[3] + red[5] + red[7]);
    }
}

// ---------------- assignment: per-block 128 points x all 1024 centroids
// t(b,k) = c2[k] - 2*dot(p_b, c_k); argmin_k t == argmin_k dist (x2 is row-constant).
__global__ __launch_bounds__(256, 2) void assign_kernel(
    const float* __restrict__ points, const float* __restrict__ centroids,
    const float* __restrict__ c2,
    float* __restrict__ o_assign, int* __restrict__ ws_assign,
    float* __restrict__ ws_tmin)
{
    __shared__ SMemU sm;
    const int tid = threadIdx.x;
    const int tx = tid & 15;          // centroid group
    const int ty = tid >> 4;          // point group
    const int bm0 = blockIdx.x * BM;

    // staging mapping: each thread loads 2 float4 per matrix per tile
    const int r0 = tid >> 2;          // row 0..63
    const int g0 = tid & 3;           // d-group (float4)

    float acc[8][8];
#pragma unroll
    for (int i = 0; i < 8; ++i)
#pragma unroll
        for (int j = 0; j < 8; ++j) acc[i][j] = 0.f;

    float mint[8];
    int   mink[8];
#pragma unroll
    for (int i = 0; i < 8; ++i) { mint[i] = FLT_MAX; mink[i] = 0; }

    float4 pa0, pa1, pb0, pb1;        // prefetch regs

    auto prefetch = [&](int tile) {
        const int nt = tile >> 4, dc = tile & 15;
        const size_t dofs = dc * BK + g0 * 4;
        const float* ap = points    + (size_t)(bm0 + r0) * Dn + dofs;
        const float* bp = centroids + (size_t)(nt * BN + r0) * Dn + dofs;
        pa0 = *(const float4*)(ap);
        pa1 = *(const float4*)(ap + (size_t)64 * Dn);
        pb0 = *(const float4*)(bp);
        pb1 = *(const float4*)(bp + (size_t)64 * Dn);
    };
    auto writeLDS = [&](int buf) {
        float* As = &sm.tiles[buf][0][0][0];
        float* Bs = &sm.tiles[buf][1][0][0];
        const int c0 = g0 * 4;
        As[(c0 + 0) * LDT + r0]      = pa0.x;
        As[(c0 + 1) * LDT + r0]      = pa0.y;
        As[(c0 + 2) * LDT + r0]      = pa0.z;
        As[(c0 + 3) * LDT + r0]      = pa0.w;
        As[(c0 + 0) * LDT + r0 + 64] = pa1.x;
        As[(c0 + 1) * LDT + r0 + 64] = pa1.y;
        As[(c0 + 2) * LDT + r0 + 64] = pa1.z;
        As[(c0 + 3) * LDT + r0 + 64] = pa1.w;
        Bs[(c0 + 0) * LDT + r0]      = pb0.x;
        Bs[(c0 + 1) * LDT + r0]      = pb0.y;
        Bs[(c0 + 2) * LDT + r0]      = pb0.z;
        Bs[(c0 + 3) * LDT + r0]      = pb0.w;
        Bs[(c0 + 0) * LDT + r0 + 64] = pb1.x;
        Bs[(c0 + 1) * LDT + r0 + 64] = pb1.y;
        Bs[(c0 + 2) * LDT + r0 + 64] = pb1.z;
        Bs[(c0 + 3) * LDT + r0 + 64] = pb1.w;
    };

    prefetch(0);
    writeLDS(0);
    __syncthreads();

    for (int tile = 0; tile < NTILES; ++tile) {
        const int buf = tile & 1;
        const bool more = (tile + 1) < NTILES;
        if (more) prefetch(tile + 1);

        const float* As = &sm.tiles[buf][0][0][0];
        const float* Bs = &sm.tiles[buf][1][0][0];
#pragma unroll
        for (int c = 0; c < BK; ++c) {
            const float4 a0 = *(const float4*)(As + c * LDT + 4 * ty);
            const float4 a1 = *(const float4*)(As + c * LDT + 64 + 4 * ty);
            const float4 b0 = *(const float4*)(Bs + c * LDT + 4 * tx);
            const float4 b1 = *(const float4*)(Bs + c * LDT + 64 + 4 * tx);
            const float av[8] = {a0.x, a0.y, a0.z, a0.w, a1.x, a1.y, a1.z, a1.w};
            const float bv[8] = {b0.x, b0.y, b0.z, b0.w, b1.x, b1.y, b1.z, b1.w};
#pragma unroll
            for (int i = 0; i < 8; ++i)
#pragma unroll
                for (int j = 0; j < 8; ++j)
                    acc[i][j] = fmaf(av[i], bv[j], acc[i][j]);
        }

        if ((tile & 15) == 15) {
            // n-tile complete: fold into per-thread running argmin, reset acc
            const int nbase = (tile >> 4) * BN;
#pragma unroll
            for (int j = 0; j < 8; ++j) {
                const int n = nbase + ((j < 4) ? (4 * tx + j) : (64 + 4 * tx + j - 4));
                const float c2n = c2[n];
#pragma unroll
                for (int i = 0; i < 8; ++i) {
                    const float tv = fmaf(-2.f, acc[i][j], c2n);
                    if (tv < mint[i] || (tv == mint[i] && n < mink[i])) {
                        mint[i] = tv; mink[i] = n;
                    }
                    acc[i][j] = 0.f;
                }
            }
        }

        if (more) {
            writeLDS(buf ^ 1);
            __syncthreads();
        }
    }

    // cross-thread (over tx) argmin per point row via LDS
    __syncthreads();
#pragma unroll
    for (int i = 0; i < 8; ++i) {
        const int m = (i < 4) ? (4 * ty + i) : (64 + 4 * ty + i - 4);
        sm.red.t[m][tx] = mint[i];
        sm.red.k[m][tx] = mink[i];
    }
    __syncthreads();
    if (tid < BM) {
        const int m = tid;
        float bt = sm.red.t[m][0];
        int   bk = sm.red.k[m][0];
#pragma unroll
        for (int x = 1; x < 16; ++x) {
            const float tv = sm.red.t[m][x];
            const int   kv = sm.red.k[m][x];
            if (tv < bt || (tv == bt && kv < bk)) { bt = tv; bk = kv; }
        }
        o_assign[bm0 + m]  = (float)bk;
        ws_assign[bm0 + m] = bk;
        ws_tmin[bm0 + m]   = bt;
    }
}

// ---------------- fused per-point pass: one wave per point
__global__ __launch_bounds__(256) void finalize_kernel(
    const float* __restrict__ points, const float* __restrict__ labels,
    const float* __restrict__ rlabels,
    const int* __restrict__ ws_assign, const float* __restrict__ ws_tmin,
    const float* __restrict__ rln,
    float* __restrict__ o_dist, float* __restrict__ o_disp,
    float* __restrict__ o_dlab, float* __restrict__ o_displab,
    float* __restrict__ o_nsum, float* __restrict__ o_nn,
    float* __restrict__ o_nlab)
{
    const int tid  = threadIdx.x;
    const int lane = tid & 63;
    const int p    = blockIdx.x * 4 + (tid >> 6);
    const int a    = ws_assign[p];

    // point row: 64 lanes x float4 = 256 floats
    const float4 pv = ((const float4*)points)[(size_t)p * 64 + lane];
    float x2 = pv.x * pv.x + pv.y * pv.y + pv.z * pv.z + pv.w * pv.w;
    const int nb = a * Dn + lane * 4;
    atomicAdd(&o_nsum[nb + 0], pv.x);
    atomicAdd(&o_nsum[nb + 1], pv.y);
    atomicAdd(&o_nsum[nb + 2], pv.z);
    atomicAdd(&o_nsum[nb + 3], pv.w);

    // label row reductions + scatter
    float l2 = 0.f, dt = 0.f;
    const float* lrow = labels  + (size_t)p * Ln;
    const float* crow = rlabels + (size_t)a * Ln;
    for (int i = lane; i < Ln; i += 64) {
        const float lv = lrow[i];
        const float cv = crow[i];
        l2 = fmaf(lv, lv, l2);
        dt = fmaf(lv, cv, dt);
        atomicAdd(&o_nlab[(size_t)a * Ln + i], lv);
    }

    for (int off = 32; off > 0; off >>= 1) {
        x2 += __shfl_down(x2, off, 64);
        l2 += __shfl_down(l2, off, 64);
        dt += __shfl_down(dt, off, 64);
    }

    if (lane == 0) {
        const float dist = x2 + ws_tmin[p];   // x2 - 2 p.c + c2
        o_dist[p] = dist;
        atomicAdd(&o_disp[a], dist);
        atomicAdd(&o_nn[a], 1.0f);
        const float dl = 1.0f - dt / (sqrtf(l2) * rln[a] + EPSF);
        o_dlab[p] = dl;
        atomicAdd(&o_displab[a], dl);
    }
}

extern "C" void kernel_launch(void* const* d_in, const int* in_sizes, int n_in,
                              void* d_out, int out_size, void* d_ws, size_t ws_size,
                              hipStream_t stream)
{
    const float* points    = (const float*)d_in[0];   // (B, D)
    const float* labels    = (const float*)d_in[1];   // (B, L)
    const float* centroids = (const float*)d_in[2];   // (K, D)
    const float* rlabels   = (const float*)d_in[3];   // (K, L)

    float* out = (float*)d_out;
    float* o_assign  = out;                       // B
    float* o_dist    = out + Bn;                  // B
    float* o_disp    = out + 2 * Bn;              // K      @ 262144
    float* o_dlab    = o_disp + Kn;               // B      @ 263168
    float* o_displab = o_dlab + Bn;               // K      @ 394240
    float* o_nsum    = o_displab + Kn;            // K*D    @ 395264
    float* o_nn      = o_nsum + Kn * Dn;          // K      @ 657408
    float* o_nlab    = o_nn + Kn;                 // K*L    @ 658432

    float* ws      = (float*)d_ws;
    float* c2      = ws;                  // K
    float* rln     = ws + Kn;             // K
    float* tmin    = ws + 2 * Kn;         // B
    int*   assigni = (int*)(ws + 2 * Kn + Bn); // B

    // zero the accumulated output regions (harness poisons with 0xAA)
    hipMemsetAsync(o_disp, 0, Kn * sizeof(float), stream);
    hipMemsetAsync(o_displab, 0,
                   (size_t)(Kn + Kn * Dn + Kn + (size_t)Kn * Ln) * sizeof(float), stream);

    prep_kernel<<<Kn, 256, 0, stream>>>(centroids, rlabels, c2, rln);
    assign_kernel<<<Bn / BM, 256, 0, stream>>>(points, centroids, c2,
                                               o_assign, assigni, tmin);
    finalize_kernel<<<Bn / 4, 256, 0, stream>>>(points, labels, rlabels,
                                                assigni, tmin, rln,
                                                o_dist, o_disp, o_dlab, o_displab,
                                                o_nsum, o_nn, o_nlab);
}